// Round 1
// 678.602 us; speedup vs baseline: 1.1339x; 1.1339x over previous
//
#include <hip/hip_runtime.h>

// B=1, H=32, N=T=2048, D=128, R=64
// out[h,n,t] = sum_d q[h,n,d]*kq[h,t,d] + (1/64)*sum_r (q@G)[h,n,r]*sign((ko-kq)@G)[h,t,r]
// Augmented-K GEMM: Qb[h][n][0:128]=bf16(q), Qb[..][128:192]=bf16(q@G)
//                   Kb[h][t][0:128]=bf16(kq), Kb[..][128:192]=sign*(1/64)
// v2: (1) prep via MFMA (hi/lo split for the sign path), LDS-free, one kernel.
//     (2) GEMM double-buffered 2-phase (stage t+1 while computing t), 1 barrier/K-step.

#define H 32
#define NQ 2048
#define NT 2048
#define D 128
#define R 64
#define KDIM 192

typedef __attribute__((ext_vector_type(4))) float f32x4;
typedef __attribute__((ext_vector_type(8))) short bf16x8;

__device__ __forceinline__ short f2bf(float x) {  // RNE f32->bf16
  union { float f; unsigned u; } v; v.f = x;
  unsigned r = v.u + 0x7fff + ((v.u >> 16) & 1);
  return (short)(r >> 16);
}
__device__ __forceinline__ float bf2f(short h) {
  union { unsigned u; float f; } v; v.u = ((unsigned)(unsigned short)h) << 16;
  return v.f;
}

__device__ __forceinline__ void gl_lds16(const void* g, void* l) {
  __builtin_amdgcn_global_load_lds(
      (const __attribute__((address_space(1))) void*)g,
      (__attribute__((address_space(3))) void*)l, 16, 0, 0);
}

// ---- prep: blocks [0,512) build Kb (sign path, hi/lo split MFMA);
//            blocks [512,1024) build Qb (q@G single-MFMA). 128 rows/block.
__global__ __launch_bounds__(256, 2) void prep(
    const float* __restrict__ q, const float* __restrict__ ko,
    const float* __restrict__ kq, const float* __restrict__ G,
    short* __restrict__ Qb, short* __restrict__ Kb) {
  const int tid = threadIdx.x, lane = tid & 63, wave = tid >> 6;
  const int quad = lane >> 4, mrow = lane & 15;
  const bool kmode = blockIdx.x < (H * NT / 128);
  const long blk = kmode ? blockIdx.x : (blockIdx.x - H * NT / 128);
  const long rbase = blk * 128 + wave * 32;  // wave owns 32 rows
  short* outb = kmode ? Kb : Qb;

  f32x4 acc[2][4] = {};

  for (int ks = 0; ks < 4; ++ks) {
    const int d0 = ks * 32 + quad * 8;
    // B-operand: columns of G. bfr[j] lane layout: n=j*16+mrow, k=quad*8+e.
    bf16x8 gh[4], gl[4];
#pragma unroll
    for (int j = 0; j < 4; ++j) {
      const float* gp = G + (size_t)d0 * R + j * 16 + mrow;
#pragma unroll
      for (int e = 0; e < 8; ++e) {
        float g = gp[(size_t)e * R];       // 4B gather, 64B-coalesced per quad, L2-hot
        short hb = f2bf(g);
        gh[j][e] = hb;
        gl[j][e] = f2bf(g - bf2f(hb));
      }
    }
    // A-operand: rows of E=ko-kq (kmode) or q. Lane layout: m=mrow, k=quad*8+e.
    bf16x8 ah[2], al[2];
#pragma unroll
    for (int i = 0; i < 2; ++i) {
      const long row = rbase + i * 16 + mrow;
      if (kmode) {
        const f32x4 a0 = *(const f32x4*)(ko + row * D + d0);
        const f32x4 a1 = *(const f32x4*)(ko + row * D + d0 + 4);
        const f32x4 b0 = *(const f32x4*)(kq + row * D + d0);
        const f32x4 b1 = *(const f32x4*)(kq + row * D + d0 + 4);
        bf16x8 kqb;
#pragma unroll
        for (int t = 0; t < 4; ++t) {
          kqb[t] = f2bf(b0[t]); kqb[t + 4] = f2bf(b1[t]);
          float e0 = a0[t] - b0[t];
          short h0 = f2bf(e0); ah[i][t] = h0; al[i][t] = f2bf(e0 - bf2f(h0));
          float e1 = a1[t] - b1[t];
          short h1 = f2bf(e1); ah[i][t + 4] = h1; al[i][t + 4] = f2bf(e1 - bf2f(h1));
        }
        *(bf16x8*)(Kb + row * KDIM + d0) = kqb;  // bf16(kq) copy, 16B store
      } else {
        const f32x4 a0 = *(const f32x4*)(q + row * D + d0);
        const f32x4 a1 = *(const f32x4*)(q + row * D + d0 + 4);
        bf16x8 qb;
#pragma unroll
        for (int t = 0; t < 4; ++t) {
          short h0 = f2bf(a0[t]); qb[t] = h0; ah[i][t] = h0; al[i][t] = 0;
          short h1 = f2bf(a1[t]); qb[t + 4] = h1; ah[i][t + 4] = h1; al[i][t + 4] = 0;
        }
        *(bf16x8*)(Qb + row * KDIM + d0) = qb;   // bf16(q) copy, 16B store
      }
    }
#pragma unroll
    for (int i = 0; i < 2; ++i)
#pragma unroll
      for (int j = 0; j < 4; ++j) {
        acc[i][j] = __builtin_amdgcn_mfma_f32_16x16x32_bf16(ah[i], gh[j], acc[i][j], 0, 0, 0);
        if (kmode) {  // hi/lo split: ~f32-accurate projection so signs don't flip
          acc[i][j] = __builtin_amdgcn_mfma_f32_16x16x32_bf16(al[i], gh[j], acc[i][j], 0, 0, 0);
          acc[i][j] = __builtin_amdgcn_mfma_f32_16x16x32_bf16(ah[i], gl[j], acc[i][j], 0, 0, 0);
        }
      }
  }
  // C/D layout (verified): col = mrow, row = quad*4 + r within each 16x16 tile.
#pragma unroll
  for (int i = 0; i < 2; ++i)
#pragma unroll
    for (int j = 0; j < 4; ++j)
#pragma unroll
      for (int r = 0; r < 4; ++r) {
        const long row = rbase + i * 16 + quad * 4 + r;
        const int col = j * 16 + mrow;
        float v = acc[i][j][r];
        short s;
        if (kmode)  // +-1/64 exact in bf16: 0x3C80 / 0xBC80
          s = v > 0.f ? (short)0x3C80 : (v < 0.f ? (short)0xBC80 : (short)0);
        else
          s = f2bf(v);
        outb[row * KDIM + 128 + col] = s;
      }
}

// ---- main GEMM: per head, 2048x2048x192, C = Qb * Kb^T, 128x128 tile,
// BK=32, double-buffered LDS, 2-phase prefetch (T3-minimum), 1 barrier/K-step.
__global__ __launch_bounds__(256, 3) void gemm_bt(const short* __restrict__ Qb,
                                                  const short* __restrict__ Kb,
                                                  float* __restrict__ out) {
  const int h  = blockIdx.z;
  const int m0 = blockIdx.y * 128;
  const int n0 = blockIdx.x * 128;
  const short* A = Qb + (size_t)h * NQ * KDIM;
  const short* B = Kb + (size_t)h * NT * KDIM;

  __shared__ __align__(16) short As[2][128 * 32];  // 2 x 8KB
  __shared__ __align__(16) short Bs[2][128 * 32];  // 2 x 8KB  (32KB total)

  const int tid = threadIdx.x, lane = tid & 63, wave = tid >> 6;
  const int wm = (wave >> 1) * 64, wn = (wave & 1) * 64;
  const int quad = lane >> 4, mrow = lane & 15;

  f32x4 acc[4][4] = {};

  // staging: thread t -> row t>>2, 16B chunk (t&3); LDS dest = wave base + lane*16
  const int srow = tid >> 2;
  const int scol = (tid & 3) * 8;
  const short* gA  = A + (size_t)(m0 + srow) * KDIM + scol;
  const short* gA2 = A + (size_t)(m0 + 64 + srow) * KDIM + scol;
  const short* gB  = B + (size_t)(n0 + srow) * KDIM + scol;
  const short* gB2 = B + (size_t)(n0 + 64 + srow) * KDIM + scol;

  auto stage = [&](int b, int kt) {
    char* a1 = (char*)(&As[b][0]) + wave * 1024;
    char* a2 = (char*)(&As[b][0]) + 4096 + wave * 1024;
    char* b1 = (char*)(&Bs[b][0]) + wave * 1024;
    char* b2 = (char*)(&Bs[b][0]) + 4096 + wave * 1024;
    gl_lds16(gA + kt * 32, a1);
    gl_lds16(gA2 + kt * 32, a2);
    gl_lds16(gB + kt * 32, b1);
    gl_lds16(gB2 + kt * 32, b2);
  };

  // prologue: stage tile 0
  stage(0, 0);
  asm volatile("s_waitcnt vmcnt(0)" ::: "memory");
  __builtin_amdgcn_s_barrier();

#pragma unroll
  for (int kt = 0; kt < 6; ++kt) {
    const int cur = kt & 1;
    if (kt < 5) stage(cur ^ 1, kt + 1);  // prefetch next tile into other buffer

    bf16x8 af[4], bfv[4];
#pragma unroll
    for (int i = 0; i < 4; ++i) {
      af[i]  = *(const bf16x8*)((const char*)(&As[cur][0]) + (wm + i * 16 + mrow) * 64 + quad * 16);
      bfv[i] = *(const bf16x8*)((const char*)(&Bs[cur][0]) + (wn + i * 16 + mrow) * 64 + quad * 16);
    }
#pragma unroll
    for (int i = 0; i < 4; ++i)
#pragma unroll
      for (int j = 0; j < 4; ++j)
        acc[i][j] = __builtin_amdgcn_mfma_f32_16x16x32_bf16(af[i], bfv[j], acc[i][j], 0, 0, 0);

    if (kt < 5) {
      asm volatile("s_waitcnt vmcnt(0)" ::: "memory");  // drain prefetch
      __builtin_amdgcn_s_barrier();                     // all waves: next buf ready
    }
  }

  // epilogue: C/D layout col=mrow, row=quad*4+reg
  float* orow = out + ((size_t)h * NQ + m0) * NT + n0;
#pragma unroll
  for (int i = 0; i < 4; ++i)
#pragma unroll
    for (int r = 0; r < 4; ++r) {
      const int row = wm + i * 16 + quad * 4 + r;
      float* p = orow + (size_t)row * NT + wn + mrow;
#pragma unroll
      for (int j = 0; j < 4; ++j) p[j * 16] = acc[i][j][r];
    }
}

extern "C" void kernel_launch(void* const* d_in, const int* in_sizes, int n_in,
                              void* d_out, int out_size, void* d_ws, size_t ws_size,
                              hipStream_t stream) {
  const float* q  = (const float*)d_in[0];
  const float* ko = (const float*)d_in[1];
  const float* kq = (const float*)d_in[2];
  const float* G  = (const float*)d_in[3];
  float* out = (float*)d_out;

  short* Kb = (short*)d_ws;
  short* Qb = Kb + (size_t)H * NT * KDIM;  // total ws: 50,331,648 B

  prep<<<(H * NT + H * NQ) / 128, 256, 0, stream>>>(q, ko, kq, G, Qb, Kb);

  dim3 grid(NT / 128, NQ / 128, H);
  gemm_bt<<<grid, 256, 0, stream>>>(Qb, Kb, out);
}